// Round 2
// baseline (394.317 us; speedup 1.0000x reference)
//
#include <hip/hip_runtime.h>

typedef float v2f __attribute__((ext_vector_type(2)));

#define KSIZE 7
#define PAD 3
#define NEG_INF (-1e30f)
#define TILE_W 128
#define TILE_H 64
#define REG_W (TILE_W + KSIZE - 1)   // 134
#define REG_H (TILE_H + KSIZE - 1)   // 70
#define LDS_STRIDE 136               // multiple of 4 floats -> b128-aligned rows
#define IMG_H 512
#define IMG_W 512

// fmaxf(a, fmaxf(b, c)) -> v_max3_f32
#define M3(a, b, c) fmaxf((a), fmaxf((b), (c)))

__global__ __launch_bounds__(256)
void GrayscaleDilation2D_kernel(const float* __restrict__ img,
                                const float* __restrict__ filt,
                                float* __restrict__ out) {
    __shared__ float tile[REG_H * LDS_STRIDE];

    const int plane = blockIdx.z;
    const int x0 = blockIdx.x * TILE_W;
    const int y0 = blockIdx.y * TILE_H;
    const float* __restrict__ src = img + (size_t)plane * IMG_H * IMG_W;
    float* __restrict__ dst = out + (size_t)plane * IMG_H * IMG_W;

    const int tx = threadIdx.x;  // 0..31
    const int ty = threadIdx.y;  // 0..7
    const int t = ty * 32 + tx;

    // Filter: wave-uniform address + static indices -> s_load into SGPRs.
    float sf[KSIZE * KSIZE];
#pragma unroll
    for (int k = 0; k < KSIZE * KSIZE; ++k) sf[k] = filt[k];

    // Stage (REG_H x REG_W) input region into LDS with NEG_INF halo.
    for (int idx = t; idx < REG_H * REG_W; idx += 256) {
        const int r = idx / REG_W;
        const int c = idx - r * REG_W;
        const int gy = y0 - PAD + r;
        const int gx = x0 - PAD + c;
        float v = NEG_INF;
        if ((unsigned)gy < IMG_H && (unsigned)gx < IMG_W)
            v = src[gy * IMG_W + gx];
        tile[r * LDS_STRIDE + c] = v;
    }
    __syncthreads();

    // Each thread: 4 wide x 8 tall output tile.
    //   rows y0 + ty*8 + o (o=0..7), cols x0 + tx*4 + l (l=0..3)
    float acc[8][4];
#pragma unroll
    for (int o = 0; o < 8; ++o)
#pragma unroll
        for (int l = 0; l < 4; ++l) acc[o][l] = NEG_INF;

    const int row0 = ty * 8;
    const int col0 = tx * 4;

#pragma unroll
    for (int r = 0; r < 14; ++r) {
        const float* rp = &tile[(row0 + r) * LDS_STRIDE + col0];
        const float4 A = *(const float4*)(rp);
        const float4 B = *(const float4*)(rp + 4);
        const float4 C = *(const float4*)(rp + 8);
        const float v[12] = {A.x, A.y, A.z, A.w, B.x, B.y, B.z, B.w,
                             C.x, C.y, C.z, C.w};
        // Sliding pairs; even c are free sub-registers of the b128 loads.
        v2f P[9];
#pragma unroll
        for (int c = 0; c < 9; ++c) P[c] = (v2f){v[c], v[c + 1]};

        // output rows using input row r: o with 0 <= r-o <= 6
        const int omin = (r - 6 < 0) ? 0 : r - 6;
        const int omax = (r < 7) ? r : 7;
#pragma unroll
        for (int o = 0; o < 8; ++o) {
            if (o < omin || o > omax) continue;  // static after unroll
            const int i = r - o;  // filter row
            v2f q0[KSIZE], q1[KSIZE];
#pragma unroll
            for (int j = 0; j < KSIZE; ++j) {
                const float f = sf[i * KSIZE + j];
                const v2f fv = {f, f};
                q0[j] = P[j] + fv;       // taps for outputs l=0,1 (v_pk_add_f32)
                q1[j] = P[j + 2] + fv;   // taps for outputs l=2,3
            }
            acc[o][0] = fmaxf(M3(acc[o][0], q0[0].x, q0[1].x),
                              M3(M3(q0[2].x, q0[3].x, q0[4].x), q0[5].x, q0[6].x));
            acc[o][1] = fmaxf(M3(acc[o][1], q0[0].y, q0[1].y),
                              M3(M3(q0[2].y, q0[3].y, q0[4].y), q0[5].y, q0[6].y));
            acc[o][2] = fmaxf(M3(acc[o][2], q1[0].x, q1[1].x),
                              M3(M3(q1[2].x, q1[3].x, q1[4].x), q1[5].x, q1[6].x));
            acc[o][3] = fmaxf(M3(acc[o][3], q1[0].y, q1[1].y),
                              M3(M3(q1[2].y, q1[3].y, q1[4].y), q1[5].y, q1[6].y));
        }
    }

#pragma unroll
    for (int o = 0; o < 8; ++o) {
        float4 res = make_float4(acc[o][0], acc[o][1], acc[o][2], acc[o][3]);
        *(float4*)&dst[(size_t)(y0 + row0 + o) * IMG_W + (x0 + col0)] = res;
    }
}

extern "C" void kernel_launch(void* const* d_in, const int* in_sizes, int n_in,
                              void* d_out, int out_size, void* d_ws, size_t ws_size,
                              hipStream_t stream) {
    const float* img  = (const float*)d_in[0];
    const float* filt = (const float*)d_in[1];
    float* out = (float*)d_out;

    const int planes = in_sizes[0] / (IMG_H * IMG_W);  // B*C = 128
    dim3 grid(IMG_W / TILE_W, IMG_H / TILE_H, planes);
    dim3 block(32, 8);
    hipLaunchKernelGGL(GrayscaleDilation2D_kernel, grid, block, 0, stream,
                       img, filt, out);
}

// Round 3
// 267.344 us; speedup vs baseline: 1.4749x; 1.4749x over previous
//
#include <hip/hip_runtime.h>

#define KSIZE 7
#define NEG_INF (-1e30f)
#define TILE_W 128
#define TILE_H 32
#define HALO_L 4                     // left halo padded to 4 for float4 alignment
#define REG_W 136                    // TILE_W + 4 left + 4 right
#define REG_H 38                     // TILE_H + 6
#define LDS_STRIDE 136               // == REG_W, multiple of 4 floats
#define IMG_H 512
#define IMG_W 512
#define N_VEC4 (REG_W / 4)           // 34 float4 per row
#define TOT_VEC4 (REG_H * N_VEC4)    // 1292 float4 slots

// fmaxf(a, fmaxf(b, c)) -> v_max3_f32
#define M3(a, b, c) fmaxf((a), fmaxf((b), (c)))

__global__ __launch_bounds__(256)
void GrayscaleDilation2D_kernel(const float* __restrict__ img,
                                const float* __restrict__ filt,
                                float* __restrict__ out) {
    __shared__ float tile[REG_H * LDS_STRIDE];

    const int plane = blockIdx.z;
    const int x0 = blockIdx.x * TILE_W;
    const int y0 = blockIdx.y * TILE_H;
    const float* __restrict__ src = img + (size_t)plane * IMG_H * IMG_W;
    float* __restrict__ dst = out + (size_t)plane * IMG_H * IMG_W;

    const int tx = threadIdx.x;  // 0..31
    const int ty = threadIdx.y;  // 0..7
    const int t = ty * 32 + tx;

    // Filter: uniform address + constant indices -> s_load into SGPRs.
    float sf[KSIZE * KSIZE];
#pragma unroll
    for (int k = 0; k < KSIZE * KSIZE; ++k) sf[k] = filt[k];

    // Stage (REG_H x REG_W) region into LDS as aligned float4.
    // x-range [x0-4, x0+131]: gx is always a multiple of 4, so each float4 is
    // either fully in-bounds or fully out (512 % 4 == 0) -> no partial loads.
#pragma unroll
    for (int it = 0; it < 6; ++it) {
        const int idx = t + it * 256;
        if (idx < TOT_VEC4) {
            const int r  = idx / N_VEC4;
            const int c4 = idx - r * N_VEC4;
            const int gy = y0 - 3 + r;
            const int gx = x0 - HALO_L + c4 * 4;
            float4 v4 = make_float4(NEG_INF, NEG_INF, NEG_INF, NEG_INF);
            if ((unsigned)gy < IMG_H && (unsigned)gx < IMG_W)
                v4 = *(const float4*)&src[gy * IMG_W + gx];
            *(float4*)&tile[r * LDS_STRIDE + c4 * 4] = v4;
        }
    }
    __syncthreads();

    // Each thread: 4x4 output tile. rows y0+ty*4+o, cols x0+tx*4+l.
    float acc[4][4];
#pragma unroll
    for (int o = 0; o < 4; ++o)
#pragma unroll
        for (int l = 0; l < 4; ++l) acc[o][l] = NEG_INF;

    const int row0 = ty * 4;
    const int col0 = tx * 4;

#pragma unroll
    for (int r = 0; r < 10; ++r) {
        const float* rp = &tile[(row0 + r) * LDS_STRIDE + col0];
        const float4 A = *(const float4*)(rp);
        const float4 B = *(const float4*)(rp + 4);
        const float4 C = *(const float4*)(rp + 8);
        // LDS col col0+k holds input col x0+col0+k-4; tap (l,j) needs v[1+l+j].
        const float v[12] = {A.x, A.y, A.z, A.w, B.x, B.y, B.z, B.w,
                             C.x, C.y, C.z, C.w};
        const int omin = (r - 6 < 0) ? 0 : r - 6;
        const int omax = (r < 3) ? r : 3;
#pragma unroll
        for (int o = 0; o < 4; ++o) {
            if (o < omin || o > omax) continue;  // static after unroll
            const int i = r - o;                 // filter row
            const float* fr = &sf[i * KSIZE];
#pragma unroll
            for (int l = 0; l < 4; ++l) {
                const float t0 = v[1 + l + 0] + fr[0];
                const float t1 = v[1 + l + 1] + fr[1];
                const float t2 = v[1 + l + 2] + fr[2];
                const float t3 = v[1 + l + 3] + fr[3];
                const float t4 = v[1 + l + 4] + fr[4];
                const float t5 = v[1 + l + 5] + fr[5];
                const float t6 = v[1 + l + 6] + fr[6];
                // 4 instrs: 3x v_max3_f32 + 1x v_max_f32 (vs 7 serial maxes)
                const float u = M3(t0, t1, t2);
                const float w = M3(t3, t4, t5);
                const float z = M3(acc[o][l], t6, u);
                acc[o][l] = fmaxf(z, w);
            }
        }
    }

#pragma unroll
    for (int o = 0; o < 4; ++o) {
        float4 res = make_float4(acc[o][0], acc[o][1], acc[o][2], acc[o][3]);
        *(float4*)&dst[(size_t)(y0 + row0 + o) * IMG_W + (x0 + col0)] = res;
    }
}

extern "C" void kernel_launch(void* const* d_in, const int* in_sizes, int n_in,
                              void* d_out, int out_size, void* d_ws, size_t ws_size,
                              hipStream_t stream) {
    const float* img  = (const float*)d_in[0];
    const float* filt = (const float*)d_in[1];
    float* out = (float*)d_out;

    const int planes = in_sizes[0] / (IMG_H * IMG_W);  // B*C = 128
    dim3 grid(IMG_W / TILE_W, IMG_H / TILE_H, planes);
    dim3 block(32, 8);
    hipLaunchKernelGGL(GrayscaleDilation2D_kernel, grid, block, 0, stream,
                       img, filt, out);
}